// Round 7
// baseline (271.818 us; speedup 1.0000x reference)
//
#include <hip/hip_runtime.h>
#include <math.h>

#define N_NODES 50000
#define N_EDGES 800000
#define F_IN    128
#define HID     64
#define HEADS   2
#define C1      128   // HEADS*HID
#define OUT_C   40
#define EDIM    5
#define NEG_SLOPE 0.2f
#define CAP1    768   // LDS edge cache, layer-1 agg (Poisson(16) => never exceeded; fallback kept)
#define CAP2    512   // LDS edge cache, layer-2 agg
#define SCAN_B  256
#define SCAN_NB ((N_NODES + SCAN_B - 1) / SCAN_B)   // 196

// ---------------- workspace layout (element offsets, 4B units) ----------------
constexpr size_t pad64(size_t n){ return (n + 63) / 64 * 64; }
constexpr size_t O_CNT      = 0;
constexpr size_t O_FILL     = O_CNT      + pad64(N_NODES);
constexpr size_t O_ZERO_END = O_FILL     + pad64(N_NODES);
constexpr size_t O_ROWPTR   = O_ZERO_END;
constexpr size_t O_STMP     = O_ROWPTR   + pad64(N_NODES+1);
constexpr size_t O_BSUM     = O_STMP     + pad64(N_NODES);
constexpr size_t O_BOFF     = O_BSUM     + pad64(SCAN_NB);
constexpr size_t O_EREC     = O_BOFF     + pad64(SCAN_NB);    // float4 per edge {src, l1h0, l1h1, l2}
constexpr size_t O_WEATT    = O_EREC     + pad64((size_t)N_EDGES*4);
constexpr size_t O_XHB      = O_WEATT    + 64;                       // bf16 [N][128] => N*64 floats
constexpr size_t O_AS1      = O_XHB      + pad64((size_t)N_NODES*C1/2);
constexpr size_t O_AD1      = O_AS1      + pad64((size_t)N_NODES*2);
constexpr size_t O_H1       = O_AD1      + pad64((size_t)N_NODES*2);
constexpr size_t O_XH2B     = O_H1       + pad64((size_t)N_NODES*C1);  // bf16 [N][40] => N*20 floats
constexpr size_t O_AS2      = O_XH2B     + pad64((size_t)N_NODES*OUT_C/2);
constexpr size_t O_AD2      = O_AS2      + pad64(N_NODES);

__device__ __forceinline__ float lrelu(float v){ return v >= 0.f ? v : NEG_SLOPE*v; }
__device__ __forceinline__ float bfl(unsigned u){ return __uint_as_float(u << 16); }
__device__ __forceinline__ float bfh(unsigned u){ return __uint_as_float(u & 0xFFFF0000u); }
__device__ __forceinline__ unsigned short f2bf(float f){
  unsigned u = __float_as_uint(f);
  return (unsigned short)((u + 0x7FFFu + ((u >> 16) & 1u)) >> 16);   // RNE
}

// ---------------- K0: tiny attention-projection matrices ----------------
__global__ void k_weatt(const float* __restrict__ We1, const float* __restrict__ ae1,
                        const float* __restrict__ We2, const float* __restrict__ ae2,
                        float* __restrict__ weatt){
  int t = threadIdx.x;
  if (t < 10){
    int k = t >> 1, h = t & 1;
    float s = 0.f;
    for (int c = 0; c < HID; c++) s += We1[k*C1 + h*HID + c] * ae1[h*HID + c];
    weatt[k*2 + h] = s;
  } else if (t < 15){
    int k = t - 10;
    float s = 0.f;
    for (int c = 0; c < OUT_C; c++) s += We2[k*OUT_C + c] * ae2[c];
    weatt[10 + k] = s;
  }
}

// ---------------- K1: in-degree (int atomics, L2-resident) ----------------
__global__ void k_count(const int* __restrict__ dst, int* __restrict__ cnt){
  int e = blockIdx.x*blockDim.x + threadIdx.x;
  if (e >= N_EDGES) return;
  atomicAdd(&cnt[dst[e]], 1);
}

// ---------------- K2: device-wide exclusive scan, 3 wide dispatches ----------------
__global__ void __launch_bounds__(SCAN_B) k_scan1(const int* __restrict__ cnt,
                                                  int* __restrict__ stmp,
                                                  int* __restrict__ bsum){
  int blk = blockIdx.x, t = threadIdx.x;
  int i = blk*SCAN_B + t;
  int v = (i < N_NODES) ? cnt[i] : 0;
  int lane = t & 63, w = t >> 6;
  int x = v;
  #pragma unroll
  for (int off = 1; off < 64; off <<= 1){
    int y = __shfl_up(x, off);
    if (lane >= off) x += y;
  }
  __shared__ int wsum[SCAN_B/64];
  if (lane == 63) wsum[w] = x;
  __syncthreads();
  int add = 0;
  for (int k = 0; k < w; k++) add += wsum[k];
  x += add;
  if (i < N_NODES) stmp[i] = x;
  if (t == SCAN_B-1) bsum[blk] = x;
}

__global__ void __launch_bounds__(SCAN_B) k_scan2(const int* __restrict__ bsum,
                                                  int* __restrict__ boff){
  int t = threadIdx.x;
  int v = (t < SCAN_NB) ? bsum[t] : 0;
  int lane = t & 63, w = t >> 6;
  int x = v;
  #pragma unroll
  for (int off = 1; off < 64; off <<= 1){
    int y = __shfl_up(x, off);
    if (lane >= off) x += y;
  }
  __shared__ int wsum[SCAN_B/64];
  if (lane == 63) wsum[w] = x;
  __syncthreads();
  int add = 0;
  for (int k = 0; k < w; k++) add += wsum[k];
  x += add;                      // inclusive
  if (t < SCAN_NB) boff[t] = x - v;  // exclusive
}

__global__ void __launch_bounds__(SCAN_B) k_scan3(const int* __restrict__ stmp,
                                                  const int* __restrict__ boff,
                                                  int* __restrict__ rowptr){
  int blk = blockIdx.x, t = threadIdx.x;
  int i = blk*SCAN_B + t;
  if (i < N_NODES) rowptr[i+1] = stmp[i] + boff[blk];
  if (i == 0) rowptr[0] = 0;
}

// ---------------- K3: scatter edges into CSR as interleaved float4 records ----------------
__global__ void k_scatter(const int* __restrict__ src, const int* __restrict__ dst,
                          const float* __restrict__ eattr, const int* __restrict__ rowptr,
                          int* __restrict__ fill, const float* __restrict__ weatt,
                          float4* __restrict__ erec){
  int e = blockIdx.x*blockDim.x + threadIdx.x;
  if (e >= N_EDGES) return;
  int d = dst[e];
  int pos = rowptr[d] + atomicAdd(&fill[d], 1);
  float a[EDIM];
  #pragma unroll
  for (int k = 0; k < EDIM; k++) a[k] = eattr[e*EDIM + k];
  float l0 = 0.f, l1 = 0.f, l2 = 0.f;
  #pragma unroll
  for (int k = 0; k < EDIM; k++){
    l0 += a[k]*weatt[k*2 + 0];
    l1 += a[k]*weatt[k*2 + 1];
    l2 += a[k]*weatt[10 + k];
  }
  erec[pos] = make_float4(__int_as_float(src[e]), l0, l1, l2);
}

// ---------------- K5: xh1 = x @ W1 (register-tiled 128x128, fused att1, bf16 out) ----------------
#define T1_ROWS 128
#define T1_KK   32
__global__ void __launch_bounds__(256) k_gemm1(const float* __restrict__ x,
                                               const float* __restrict__ W,
                                               const float* __restrict__ a_src,
                                               const float* __restrict__ a_dst,
                                               unsigned short* __restrict__ xhb,
                                               float* __restrict__ as_o,
                                               float* __restrict__ ad_o){
  __shared__ float xs[T1_ROWS][T1_KK+1];
  __shared__ float ws[T1_KK][C1];
  int tid = threadIdx.x;
  int tx = tid & 15, ty = tid >> 4;
  int r0 = blockIdx.x * T1_ROWS;
  float acc[8][8];
  #pragma unroll
  for (int i = 0; i < 8; i++)
    #pragma unroll
    for (int j = 0; j < 8; j++) acc[i][j] = 0.f;

  for (int kb = 0; kb < F_IN; kb += T1_KK){
    __syncthreads();
    for (int i = tid; i < T1_ROWS*(T1_KK/4); i += 256){
      int r = i >> 3, c4 = (i & 7) * 4;
      int row = r0 + r;
      float4 v = (row < N_NODES) ? *(const float4*)&x[(size_t)row*F_IN + kb + c4]
                                 : make_float4(0.f,0.f,0.f,0.f);
      xs[r][c4+0]=v.x; xs[r][c4+1]=v.y; xs[r][c4+2]=v.z; xs[r][c4+3]=v.w;
    }
    for (int i = tid; i < T1_KK*(C1/4); i += 256){
      int k = i >> 5, c4 = (i & 31) * 4;
      *(float4*)&ws[k][c4] = *(const float4*)&W[(size_t)(kb + k)*C1 + c4];
    }
    __syncthreads();
    #pragma unroll 4
    for (int k = 0; k < T1_KK; k++){
      float a[8], b[8];
      #pragma unroll
      for (int i = 0; i < 8; i++) a[i] = xs[ty*8 + i][k];
      float4 b0 = *(const float4*)&ws[k][tx*8];
      float4 b1 = *(const float4*)&ws[k][tx*8+4];
      b[0]=b0.x; b[1]=b0.y; b[2]=b0.z; b[3]=b0.w;
      b[4]=b1.x; b[5]=b1.y; b[6]=b1.z; b[7]=b1.w;
      #pragma unroll
      for (int i = 0; i < 8; i++)
        #pragma unroll
        for (int j = 0; j < 8; j++)
          acc[i][j] += a[i]*b[j];
    }
  }
  float asv[8], adv[8];
  #pragma unroll
  for (int j = 0; j < 8; j++){
    asv[j] = a_src[tx*8 + j];
    adv[j] = a_dst[tx*8 + j];
  }
  int h = tx >> 3;
  #pragma unroll
  for (int i = 0; i < 8; i++){
    int row = r0 + ty*8 + i;
    bool ok = row < N_NODES;
    if (ok){
      unsigned short hh[8];
      #pragma unroll
      for (int j = 0; j < 8; j++) hh[j] = f2bf(acc[i][j]);
      uint4 pk;
      pk.x = (unsigned)hh[0] | ((unsigned)hh[1] << 16);
      pk.y = (unsigned)hh[2] | ((unsigned)hh[3] << 16);
      pk.z = (unsigned)hh[4] | ((unsigned)hh[5] << 16);
      pk.w = (unsigned)hh[6] | ((unsigned)hh[7] << 16);
      *(uint4*)&xhb[(size_t)row*C1 + tx*8] = pk;
    }
    float s = 0.f, d = 0.f;
    #pragma unroll
    for (int j = 0; j < 8; j++){ s += acc[i][j]*asv[j]; d += acc[i][j]*adv[j]; }
    s += __shfl_xor(s, 1); s += __shfl_xor(s, 2); s += __shfl_xor(s, 4);
    d += __shfl_xor(d, 1); d += __shfl_xor(d, 2); d += __shfl_xor(d, 4);
    if (ok && (tx & 7) == 0){
      as_o[row*2 + h] = s;
      ad_o[row*2 + h] = d;
    }
  }
}

// ---------------- K7: layer-1 aggregation; bf16 gather, 8 edges x 16 lanes x 8 cols ----------------
__global__ void __launch_bounds__(128) k_agg1(const unsigned short* __restrict__ xhb,
    const int* __restrict__ rowptr, const float4* __restrict__ erec,
    const float* __restrict__ as1, const float* __restrict__ ad1,
    const float* __restrict__ b1, float* __restrict__ h1){
  __shared__ int   srcA[CAP1];
  __shared__ float e0A[CAP1], e1A[CAP1];
  __shared__ float red[2][4];
  __shared__ float xw[128];
  int n = blockIdx.x, t = threadIdx.x;
  int w = t >> 6, lane = t & 63;
  int beg = rowptr[n], end = rowptr[n+1];
  int deg = end - beg;
  float ad0 = ad1[n*2+0], adv1 = ad1[n*2+1];
  float inv = 1.f / fmaxf((float)deg, 1.f);

  if (deg <= CAP1){
    // pass A (single pass): exp(logit) -> LDS; accumulate sums; logits bounded (~|8|) so no max needed
    float s0 = 0.f, s1 = 0.f, la0 = 0.f, la1 = 0.f;
    for (int i = t; i < deg; i += 128){
      float4 r = erec[(size_t)beg + i];
      int s = __float_as_int(r.x);
      float2 a = *(const float2*)&as1[s*2];
      float e0 = expf(lrelu(a.x + ad0  + r.y));
      float e1 = expf(lrelu(a.y + adv1 + r.z));
      srcA[i] = s * C1;
      e0A[i] = e0; e1A[i] = e1;
      s0 += e0; s1 += e1;
      la0 += r.y; la1 += r.z;
    }
    #pragma unroll
    for (int off = 1; off < 64; off <<= 1){
      s0 += __shfl_xor(s0, off); s1 += __shfl_xor(s1, off);
      la0 += __shfl_xor(la0, off); la1 += __shfl_xor(la1, off);
    }
    if (lane == 0){ red[w][0]=s0; red[w][1]=s1; red[w][2]=la0; red[w][3]=la1; }
    __syncthreads();
    float la0t = red[0][2] + red[1][2], la1t = red[0][3] + red[1][3];
    float sl0 = lrelu(as1[n*2+0] + ad0  + la0t*inv);
    float sl1 = lrelu(as1[n*2+1] + adv1 + la1t*inv);
    float es0 = expf(sl0), es1 = expf(sl1);
    float S0 = red[0][0] + red[1][0] + es0;
    float S1 = red[0][1] + red[1][1] + es1;

    // phase B: 8 edge-groups x 16 lanes; each lane = 8 bf16 cols (16B load)
    int g = t >> 4, l16 = t & 15;
    const float* eSel = (l16 < 8) ? e0A : e1A;
    float acc[8];
    #pragma unroll
    for (int j = 0; j < 8; j++) acc[j] = 0.f;
    for (int k0 = 0; k0 < deg; k0 += 8){
      int k = k0 + g;
      if (k < deg){
        float e = eSel[k];
        uint4 r = *(const uint4*)&xhb[srcA[k] + l16*8];
        acc[0] += e*bfl(r.x); acc[1] += e*bfh(r.x);
        acc[2] += e*bfl(r.y); acc[3] += e*bfh(r.y);
        acc[4] += e*bfl(r.z); acc[5] += e*bfh(r.z);
        acc[6] += e*bfl(r.w); acc[7] += e*bfh(r.w);
      }
    }
    // reduce 4 groups within wave, then across waves via LDS
    #pragma unroll
    for (int j = 0; j < 8; j++){
      acc[j] += __shfl_xor(acc[j], 16);
      acc[j] += __shfl_xor(acc[j], 32);
    }
    if (w == 1 && lane < 16){
      #pragma unroll
      for (int j = 0; j < 8; j++) xw[lane*8 + j] = acc[j];
    }
    __syncthreads();
    if (t < 16){
      float es = (t < 8) ? es0 : es1;
      float den = ((t < 8) ? S0 : S1) + 1e-16f;
      uint4 r = *(const uint4*)&xhb[(size_t)n*C1 + t*8];
      float xs8[8];
      xs8[0]=bfl(r.x); xs8[1]=bfh(r.x); xs8[2]=bfl(r.y); xs8[3]=bfh(r.y);
      xs8[4]=bfl(r.z); xs8[5]=bfh(r.z); xs8[6]=bfl(r.w); xs8[7]=bfh(r.w);
      float o[8];
      #pragma unroll
      for (int j = 0; j < 8; j++){
        float v = (acc[j] + xw[t*8 + j] + es*xs8[j]) / den + b1[t*8 + j];
        o[j] = v > 0.f ? v : expm1f(v);   // ELU
      }
      *(float4*)&h1[(size_t)n*C1 + t*8]     = make_float4(o[0],o[1],o[2],o[3]);
      *(float4*)&h1[(size_t)n*C1 + t*8 + 4] = make_float4(o[4],o[5],o[6],o[7]);
    }
    return;
  }

  // fallback (deg > CAP1): 3-pass recompute with max, column-per-thread — ~never taken
  {
    __shared__ float mW[2][2], laW[2][2], sW[2][2];
    float m0 = -INFINITY, m1 = -INFINITY, la0 = 0.f, la1 = 0.f;
    for (int i = t; i < deg; i += 128){
      float4 r = erec[(size_t)beg + i];
      int s = __float_as_int(r.x);
      float2 a = *(const float2*)&as1[s*2];
      m0 = fmaxf(m0, lrelu(a.x + ad0  + r.y));
      m1 = fmaxf(m1, lrelu(a.y + adv1 + r.z));
      la0 += r.y; la1 += r.z;
    }
    for (int off = 1; off < 64; off <<= 1){
      m0 = fmaxf(m0, __shfl_xor(m0, off));
      m1 = fmaxf(m1, __shfl_xor(m1, off));
      la0 += __shfl_xor(la0, off); la1 += __shfl_xor(la1, off);
    }
    if (lane == 0){ mW[w][0]=m0; mW[w][1]=m1; laW[w][0]=la0; laW[w][1]=la1; }
    __syncthreads();
    float M0 = fmaxf(mW[0][0], mW[1][0]);
    float M1 = fmaxf(mW[0][1], mW[1][1]);
    float sl0 = lrelu(as1[n*2+0] + ad0  + (laW[0][0]+laW[1][0])*inv);
    float sl1 = lrelu(as1[n*2+1] + adv1 + (laW[0][1]+laW[1][1])*inv);
    M0 = fmaxf(M0, sl0); M1 = fmaxf(M1, sl1);
    float s0 = 0.f, s1 = 0.f;
    for (int i = t; i < deg; i += 128){
      float4 r = erec[(size_t)beg + i];
      int s = __float_as_int(r.x);
      float2 a = *(const float2*)&as1[s*2];
      s0 += expf(lrelu(a.x + ad0  + r.y) - M0);
      s1 += expf(lrelu(a.y + adv1 + r.z) - M1);
    }
    for (int off = 1; off < 64; off <<= 1){
      s0 += __shfl_xor(s0, off); s1 += __shfl_xor(s1, off);
    }
    if (lane == 0){ sW[w][0]=s0; sW[w][1]=s1; }
    __syncthreads();
    float es0 = expf(sl0 - M0), es1 = expf(sl1 - M1);
    float S0 = sW[0][0] + sW[1][0] + es0;
    float S1 = sW[0][1] + sW[1][1] + es1;
    const float* eSel = (t < 64) ? e0A : e1A;
    float acc = 0.f;
    for (int base = 0; base < deg; base += CAP1){
      int c = min(CAP1, deg - base);
      __syncthreads();
      for (int i = t; i < c; i += 128){
        float4 r = erec[(size_t)beg + base + i];
        int s = __float_as_int(r.x);
        float2 a = *(const float2*)&as1[s*2];
        srcA[i] = s * C1;
        e0A[i] = expf(lrelu(a.x + ad0  + r.y) - M0);
        e1A[i] = expf(lrelu(a.y + adv1 + r.z) - M1);
      }
      __syncthreads();
      for (int k = 0; k < c; ++k)
        acc += eSel[k] * __uint_as_float(((unsigned)xhb[(size_t)(srcA[k] + t)]) << 16);
    }
    acc += ((t < 64) ? es0 : es1) * __uint_as_float(((unsigned)xhb[(size_t)n*C1 + t]) << 16);
    float v = acc / (((t < 64) ? S0 : S1) + 1e-16f) + b1[t];
    h1[(size_t)n*C1 + t] = v > 0.f ? v : expm1f(v);   // ELU
  }
}

// ---------------- K8: xh2 = h1 @ W2 (register-tiled, fused att2, bf16 out) ----------------
#define T2_ROWS 128
#define T2_KK   32
__global__ void __launch_bounds__(256) k_gemm2(const float* __restrict__ h1,
    const float* __restrict__ W2, const float* __restrict__ a_src2,
    const float* __restrict__ a_dst2,
    unsigned short* __restrict__ xh2b, float* __restrict__ as_o, float* __restrict__ ad_o){
  __shared__ float hs[T2_ROWS][T2_KK+1];
  __shared__ float ws[F_IN*OUT_C];     // full W2, 20.5 KB
  int tid = threadIdx.x;
  int tx = tid & 7, ty = tid >> 3;     // tx: 8 col-groups of 5, ty: 32 row-groups of 4
  int r0 = blockIdx.x * T2_ROWS;
  for (int i = tid; i < F_IN*OUT_C/4; i += 256)
    ((float4*)ws)[i] = ((const float4*)W2)[i];
  float acc[4][5];
  #pragma unroll
  for (int i = 0; i < 4; i++)
    #pragma unroll
    for (int j = 0; j < 5; j++) acc[i][j] = 0.f;

  for (int kb = 0; kb < F_IN; kb += T2_KK){
    __syncthreads();
    for (int i = tid; i < T2_ROWS*(T2_KK/4); i += 256){
      int r = i >> 3, c4 = (i & 7) * 4;
      int row = r0 + r;
      float4 v = (row < N_NODES) ? *(const float4*)&h1[(size_t)row*F_IN + kb + c4]
                                 : make_float4(0.f,0.f,0.f,0.f);
      hs[r][c4+0]=v.x; hs[r][c4+1]=v.y; hs[r][c4+2]=v.z; hs[r][c4+3]=v.w;
    }
    __syncthreads();
    #pragma unroll 4
    for (int k = 0; k < T2_KK; k++){
      float a[4], b[5];
      #pragma unroll
      for (int i = 0; i < 4; i++) a[i] = hs[ty*4 + i][k];
      #pragma unroll
      for (int j = 0; j < 5; j++) b[j] = ws[(kb + k)*OUT_C + tx*5 + j];
      #pragma unroll
      for (int i = 0; i < 4; i++)
        #pragma unroll
        for (int j = 0; j < 5; j++)
          acc[i][j] += a[i]*b[j];
    }
  }
  float asv[5], adv[5];
  #pragma unroll
  for (int j = 0; j < 5; j++){
    asv[j] = a_src2[tx*5 + j];
    adv[j] = a_dst2[tx*5 + j];
  }
  #pragma unroll
  for (int i = 0; i < 4; i++){
    int row = r0 + ty*4 + i;
    bool ok = row < N_NODES;
    if (ok){
      #pragma unroll
      for (int j = 0; j < 5; j++)
        xh2b[(size_t)row*OUT_C + tx*5 + j] = f2bf(acc[i][j]);
    }
    float s = 0.f, d = 0.f;
    #pragma unroll
    for (int j = 0; j < 5; j++){ s += acc[i][j]*asv[j]; d += acc[i][j]*adv[j]; }
    s += __shfl_xor(s, 1); s += __shfl_xor(s, 2); s += __shfl_xor(s, 4);
    d += __shfl_xor(d, 1); d += __shfl_xor(d, 2); d += __shfl_xor(d, 4);
    if (ok && tx == 0){
      as_o[row] = s;
      ad_o[row] = d;
    }
  }
}

// ---------------- K10: layer-2 aggregation + log_softmax, bf16 gather ----------------
__global__ void __launch_bounds__(64) k_agg2(const unsigned short* __restrict__ xh2b,
    const int* __restrict__ rowptr, const float4* __restrict__ erec,
    const float* __restrict__ as2, const float* __restrict__ ad2,
    const float* __restrict__ b2, float* __restrict__ out){
  __shared__ int   srcA[CAP2];
  __shared__ float eA[CAP2];
  int n = blockIdx.x, t = threadIdx.x;
  int beg = rowptr[n], end = rowptr[n+1];
  int deg = end - beg;
  float adv = ad2[n];
  float inv = 1.f / fmaxf((float)deg, 1.f);
  float o0 = -INFINITY, o1 = -INFINITY;

  if (deg <= CAP2){
    // pass A single-pass (bounded logits)
    float ss = 0.f, la = 0.f;
    for (int i = t; i < deg; i += 64){
      float4 r = erec[(size_t)beg + i];
      int s = __float_as_int(r.x);
      float e = expf(lrelu(as2[s] + adv + r.w));
      srcA[i] = s * OUT_C;
      eA[i] = e;
      ss += e;
      la += r.w;
    }
    #pragma unroll
    for (int off = 1; off < 64; off <<= 1){
      ss += __shfl_xor(ss, off);
      la += __shfl_xor(la, off);
    }
    float sl = lrelu(as2[n] + adv + la*inv);
    float es = expf(sl);
    float S = ss + es + 1e-16f;
    __syncthreads();
    // phase B: 2 edge-groups x 32 lanes; lanes 0..19 each hold cols {2c, 2c+1}
    int g = t >> 5, l32 = t & 31;
    float a0 = 0.f, a1 = 0.f;
    for (int k0 = 0; k0 < deg; k0 += 2){
      int k = k0 + g;
      if (k < deg && l32 < 20){
        float e = eA[k];
        unsigned u = *(const unsigned*)&xh2b[srcA[k] + l32*2];
        a0 += e*bfl(u); a1 += e*bfh(u);
      }
    }
    a0 += __shfl_xor(a0, 32);
    a1 += __shfl_xor(a1, 32);
    if (t < 20){
      unsigned u = *(const unsigned*)&xh2b[(size_t)n*OUT_C + t*2];
      o0 = (a0 + es*bfl(u)) / S + b2[t*2 + 0];
      o1 = (a1 + es*bfh(u)) / S + b2[t*2 + 1];
    }
  } else {
    // fallback with max, ~never taken
    float m = -INFINITY, la = 0.f;
    for (int i = t; i < deg; i += 64){
      float4 r = erec[(size_t)beg + i];
      int s = __float_as_int(r.x);
      m = fmaxf(m, lrelu(as2[s] + adv + r.w));
      la += r.w;
    }
    for (int off = 1; off < 64; off <<= 1){
      m = fmaxf(m, __shfl_xor(m, off));
      la += __shfl_xor(la, off);
    }
    float sl = lrelu(as2[n] + adv + la*inv);
    float M = fmaxf(m, sl);
    float ss = 0.f;
    for (int i = t; i < deg; i += 64){
      float4 r = erec[(size_t)beg + i];
      int s = __float_as_int(r.x);
      ss += expf(lrelu(as2[s] + adv + r.w) - M);
    }
    for (int off = 1; off < 64; off <<= 1) ss += __shfl_xor(ss, off);
    float es = expf(sl - M);
    float S = ss + es + 1e-16f;
    float acc0 = 0.f, acc1 = 0.f;
    for (int base = 0; base < deg; base += CAP2){
      int c = min(CAP2, deg - base);
      __syncthreads();
      for (int i = t; i < c; i += 64){
        float4 r = erec[(size_t)beg + base + i];
        int s = __float_as_int(r.x);
        srcA[i] = s * OUT_C;
        eA[i] = expf(lrelu(as2[s] + adv + r.w) - M);
      }
      __syncthreads();
      if (t < 20){
        for (int k = 0; k < c; ++k){
          unsigned u = *(const unsigned*)&xh2b[srcA[k] + t*2];
          acc0 += eA[k]*bfl(u); acc1 += eA[k]*bfh(u);
        }
      }
    }
    if (t < 20){
      unsigned u = *(const unsigned*)&xh2b[(size_t)n*OUT_C + t*2];
      o0 = (acc0 + es*bfl(u)) / S + b2[t*2 + 0];
      o1 = (acc1 + es*bfh(u)) / S + b2[t*2 + 1];
    }
  }
  // log_softmax over 40 cols (2 per lane in lanes 0..19; others -inf/0)
  float mm = fmaxf(o0, o1);
  #pragma unroll
  for (int off = 1; off < 32; off <<= 1) mm = fmaxf(mm, __shfl_xor(mm, off));
  float e = ((t < 20) ? expf(o0 - mm) : 0.f) + ((t < 20) ? expf(o1 - mm) : 0.f);
  #pragma unroll
  for (int off = 1; off < 32; off <<= 1) e += __shfl_xor(e, off);
  if (t < 20){
    float lse = logf(e);
    out[(size_t)n*OUT_C + t*2 + 0] = o0 - mm - lse;
    out[(size_t)n*OUT_C + t*2 + 1] = o1 - mm - lse;
  }
}

// ---------------- host launcher ----------------
extern "C" void kernel_launch(void* const* d_in, const int* in_sizes, int n_in,
                              void* d_out, int out_size, void* d_ws, size_t ws_size,
                              hipStream_t stream){
  const float* x        = (const float*)d_in[0];
  const int*   ei       = (const int*)  d_in[1];
  const float* eattr    = (const float*)d_in[2];
  const float* W1       = (const float*)d_in[3];
  const float* att_src1 = (const float*)d_in[4];
  const float* att_dst1 = (const float*)d_in[5];
  const float* We1      = (const float*)d_in[6];
  const float* att_e1   = (const float*)d_in[7];
  const float* b1       = (const float*)d_in[8];
  const float* W2       = (const float*)d_in[9];
  const float* att_src2 = (const float*)d_in[10];
  const float* att_dst2 = (const float*)d_in[11];
  const float* We2      = (const float*)d_in[12];
  const float* att_e2   = (const float*)d_in[13];
  const float* b2       = (const float*)d_in[14];
  const int* src = ei;
  const int* dst = ei + N_EDGES;

  float* wsf    = (float*)d_ws;
  int*   cnt     = (int*)(wsf + O_CNT);
  int*   fill    = (int*)(wsf + O_FILL);
  int*   rowptr  = (int*)(wsf + O_ROWPTR);
  int*   stmp    = (int*)(wsf + O_STMP);
  int*   bsum    = (int*)(wsf + O_BSUM);
  int*   boff    = (int*)(wsf + O_BOFF);
  float4* erec   = (float4*)(wsf + O_EREC);
  float* weatt   = wsf + O_WEATT;
  unsigned short* xhb  = (unsigned short*)(wsf + O_XHB);
  float* as1     = wsf + O_AS1;
  float* ad1     = wsf + O_AD1;
  float* h1      = wsf + O_H1;
  unsigned short* xh2b = (unsigned short*)(wsf + O_XH2B);
  float* as2     = wsf + O_AS2;
  float* ad2     = wsf + O_AD2;
  float* out     = (float*)d_out;

  hipMemsetAsync(wsf + O_CNT, 0, O_ZERO_END*sizeof(float), stream);

  const int EB = (N_EDGES + 255) / 256;

  k_weatt  <<<1, 64, 0, stream>>>(We1, att_e1, We2, att_e2, weatt);
  k_count  <<<EB, 256, 0, stream>>>(dst, cnt);
  k_scan1  <<<SCAN_NB, SCAN_B, 0, stream>>>(cnt, stmp, bsum);
  k_scan2  <<<1, SCAN_B, 0, stream>>>(bsum, boff);
  k_scan3  <<<SCAN_NB, SCAN_B, 0, stream>>>(stmp, boff, rowptr);
  k_scatter<<<EB, 256, 0, stream>>>(src, dst, eattr, rowptr, fill, weatt, erec);

  k_gemm1  <<<(N_NODES + T1_ROWS - 1)/T1_ROWS, 256, 0, stream>>>(x, W1, att_src1, att_dst1,
                                                                 xhb, as1, ad1);
  k_agg1   <<<N_NODES, 128, 0, stream>>>(xhb, rowptr, erec, as1, ad1, b1, h1);

  k_gemm2  <<<(N_NODES + T2_ROWS - 1)/T2_ROWS, 256, 0, stream>>>(h1, W2, att_src2, att_dst2,
                                                                 xh2b, as2, ad2);
  k_agg2   <<<N_NODES, 64, 0, stream>>>(xh2b, rowptr, erec, as2, ad2, b2, out);
}

// Round 8
// 222.032 us; speedup vs baseline: 1.2242x; 1.2242x over previous
//
#include <hip/hip_runtime.h>
#include <math.h>

#define N_NODES 50000
#define N_EDGES 800000
#define F_IN    128
#define HID     64
#define HEADS   2
#define C1      128   // HEADS*HID
#define OUT_C   40
#define EDIM    5
#define NEG_SLOPE 0.2f
#define CAPN    64    // per-node LDS edge cache (Poisson(16): P(deg>64)~1e-20; fallback kept)
#define NPB1    16    // nodes per block, layer-1 agg (16 lanes/node)
#define NPB2    8     // nodes per block, layer-2 agg (32 lanes/node)
#define SCAN_B  256
#define SCAN_NB ((N_NODES + SCAN_B - 1) / SCAN_B)   // 196

// ---------------- workspace layout (element offsets, 4B units) ----------------
constexpr size_t pad64(size_t n){ return (n + 63) / 64 * 64; }
constexpr size_t O_CNT      = 0;
constexpr size_t O_FILL     = O_CNT      + pad64(N_NODES);
constexpr size_t O_ZERO_END = O_FILL     + pad64(N_NODES);
constexpr size_t O_ROWPTR   = O_ZERO_END;
constexpr size_t O_STMP     = O_ROWPTR   + pad64(N_NODES+1);
constexpr size_t O_BSUM     = O_STMP     + pad64(N_NODES);
constexpr size_t O_BOFF     = O_BSUM     + pad64(SCAN_NB);
constexpr size_t O_EREC     = O_BOFF     + pad64(SCAN_NB);    // float4 per edge {src, l1h0, l1h1, l2}
constexpr size_t O_WEATT    = O_EREC     + pad64((size_t)N_EDGES*4);
constexpr size_t O_XHB      = O_WEATT    + 64;                       // bf16 [N][128]
constexpr size_t O_AS1      = O_XHB      + pad64((size_t)N_NODES*C1/2);
constexpr size_t O_AD1      = O_AS1      + pad64((size_t)N_NODES*2);
constexpr size_t O_H1       = O_AD1      + pad64((size_t)N_NODES*2);
constexpr size_t O_XH2B     = O_H1       + pad64((size_t)N_NODES*C1);  // bf16 [N][40]
constexpr size_t O_AS2      = O_XH2B     + pad64((size_t)N_NODES*OUT_C/2);
constexpr size_t O_AD2      = O_AS2      + pad64(N_NODES);

__device__ __forceinline__ float lrelu(float v){ return v >= 0.f ? v : NEG_SLOPE*v; }
__device__ __forceinline__ float bfl(unsigned u){ return __uint_as_float(u << 16); }
__device__ __forceinline__ float bfh(unsigned u){ return __uint_as_float(u & 0xFFFF0000u); }
__device__ __forceinline__ unsigned short f2bf(float f){
  unsigned u = __float_as_uint(f);
  return (unsigned short)((u + 0x7FFFu + ((u >> 16) & 1u)) >> 16);   // RNE
}

// ---------------- K0: tiny attention-projection matrices ----------------
__global__ void k_weatt(const float* __restrict__ We1, const float* __restrict__ ae1,
                        const float* __restrict__ We2, const float* __restrict__ ae2,
                        float* __restrict__ weatt){
  int t = threadIdx.x;
  if (t < 10){
    int k = t >> 1, h = t & 1;
    float s = 0.f;
    for (int c = 0; c < HID; c++) s += We1[k*C1 + h*HID + c] * ae1[h*HID + c];
    weatt[k*2 + h] = s;
  } else if (t < 15){
    int k = t - 10;
    float s = 0.f;
    for (int c = 0; c < OUT_C; c++) s += We2[k*OUT_C + c] * ae2[c];
    weatt[10 + k] = s;
  }
}

// ---------------- K1: in-degree (int atomics, L2-resident) ----------------
__global__ void k_count(const int* __restrict__ dst, int* __restrict__ cnt){
  int e = blockIdx.x*blockDim.x + threadIdx.x;
  if (e >= N_EDGES) return;
  atomicAdd(&cnt[dst[e]], 1);
}

// ---------------- K2: device-wide exclusive scan, 3 wide dispatches ----------------
__global__ void __launch_bounds__(SCAN_B) k_scan1(const int* __restrict__ cnt,
                                                  int* __restrict__ stmp,
                                                  int* __restrict__ bsum){
  int blk = blockIdx.x, t = threadIdx.x;
  int i = blk*SCAN_B + t;
  int v = (i < N_NODES) ? cnt[i] : 0;
  int lane = t & 63, w = t >> 6;
  int x = v;
  #pragma unroll
  for (int off = 1; off < 64; off <<= 1){
    int y = __shfl_up(x, off);
    if (lane >= off) x += y;
  }
  __shared__ int wsum[SCAN_B/64];
  if (lane == 63) wsum[w] = x;
  __syncthreads();
  int add = 0;
  for (int k = 0; k < w; k++) add += wsum[k];
  x += add;
  if (i < N_NODES) stmp[i] = x;
  if (t == SCAN_B-1) bsum[blk] = x;
}

__global__ void __launch_bounds__(SCAN_B) k_scan2(const int* __restrict__ bsum,
                                                  int* __restrict__ boff){
  int t = threadIdx.x;
  int v = (t < SCAN_NB) ? bsum[t] : 0;
  int lane = t & 63, w = t >> 6;
  int x = v;
  #pragma unroll
  for (int off = 1; off < 64; off <<= 1){
    int y = __shfl_up(x, off);
    if (lane >= off) x += y;
  }
  __shared__ int wsum[SCAN_B/64];
  if (lane == 63) wsum[w] = x;
  __syncthreads();
  int add = 0;
  for (int k = 0; k < w; k++) add += wsum[k];
  x += add;                      // inclusive
  if (t < SCAN_NB) boff[t] = x - v;  // exclusive
}

__global__ void __launch_bounds__(SCAN_B) k_scan3(const int* __restrict__ stmp,
                                                  const int* __restrict__ boff,
                                                  int* __restrict__ rowptr){
  int blk = blockIdx.x, t = threadIdx.x;
  int i = blk*SCAN_B + t;
  if (i < N_NODES) rowptr[i+1] = stmp[i] + boff[blk];
  if (i == 0) rowptr[0] = 0;
}

// ---------------- K3: scatter edges into CSR as interleaved float4 records ----------------
__global__ void k_scatter(const int* __restrict__ src, const int* __restrict__ dst,
                          const float* __restrict__ eattr, const int* __restrict__ rowptr,
                          int* __restrict__ fill, const float* __restrict__ weatt,
                          float4* __restrict__ erec){
  int e = blockIdx.x*blockDim.x + threadIdx.x;
  if (e >= N_EDGES) return;
  int d = dst[e];
  int pos = rowptr[d] + atomicAdd(&fill[d], 1);
  float a[EDIM];
  #pragma unroll
  for (int k = 0; k < EDIM; k++) a[k] = eattr[e*EDIM + k];
  float l0 = 0.f, l1 = 0.f, l2 = 0.f;
  #pragma unroll
  for (int k = 0; k < EDIM; k++){
    l0 += a[k]*weatt[k*2 + 0];
    l1 += a[k]*weatt[k*2 + 1];
    l2 += a[k]*weatt[10 + k];
  }
  erec[pos] = make_float4(__int_as_float(src[e]), l0, l1, l2);
}

// ---------------- K5: xh1 = x @ W1 (register-tiled 128x128, fused att1, bf16 out) ----------------
#define T1_ROWS 128
#define T1_KK   32
__global__ void __launch_bounds__(256) k_gemm1(const float* __restrict__ x,
                                               const float* __restrict__ W,
                                               const float* __restrict__ a_src,
                                               const float* __restrict__ a_dst,
                                               unsigned short* __restrict__ xhb,
                                               float* __restrict__ as_o,
                                               float* __restrict__ ad_o){
  __shared__ float xs[T1_ROWS][T1_KK+1];
  __shared__ float ws[T1_KK][C1];
  int tid = threadIdx.x;
  int tx = tid & 15, ty = tid >> 4;
  int r0 = blockIdx.x * T1_ROWS;
  float acc[8][8];
  #pragma unroll
  for (int i = 0; i < 8; i++)
    #pragma unroll
    for (int j = 0; j < 8; j++) acc[i][j] = 0.f;

  for (int kb = 0; kb < F_IN; kb += T1_KK){
    __syncthreads();
    for (int i = tid; i < T1_ROWS*(T1_KK/4); i += 256){
      int r = i >> 3, c4 = (i & 7) * 4;
      int row = r0 + r;
      float4 v = (row < N_NODES) ? *(const float4*)&x[(size_t)row*F_IN + kb + c4]
                                 : make_float4(0.f,0.f,0.f,0.f);
      xs[r][c4+0]=v.x; xs[r][c4+1]=v.y; xs[r][c4+2]=v.z; xs[r][c4+3]=v.w;
    }
    for (int i = tid; i < T1_KK*(C1/4); i += 256){
      int k = i >> 5, c4 = (i & 31) * 4;
      *(float4*)&ws[k][c4] = *(const float4*)&W[(size_t)(kb + k)*C1 + c4];
    }
    __syncthreads();
    #pragma unroll 4
    for (int k = 0; k < T1_KK; k++){
      float a[8], b[8];
      #pragma unroll
      for (int i = 0; i < 8; i++) a[i] = xs[ty*8 + i][k];
      float4 b0 = *(const float4*)&ws[k][tx*8];
      float4 b1 = *(const float4*)&ws[k][tx*8+4];
      b[0]=b0.x; b[1]=b0.y; b[2]=b0.z; b[3]=b0.w;
      b[4]=b1.x; b[5]=b1.y; b[6]=b1.z; b[7]=b1.w;
      #pragma unroll
      for (int i = 0; i < 8; i++)
        #pragma unroll
        for (int j = 0; j < 8; j++)
          acc[i][j] += a[i]*b[j];
    }
  }
  float asv[8], adv[8];
  #pragma unroll
  for (int j = 0; j < 8; j++){
    asv[j] = a_src[tx*8 + j];
    adv[j] = a_dst[tx*8 + j];
  }
  int h = tx >> 3;
  #pragma unroll
  for (int i = 0; i < 8; i++){
    int row = r0 + ty*8 + i;
    bool ok = row < N_NODES;
    if (ok){
      unsigned short hh[8];
      #pragma unroll
      for (int j = 0; j < 8; j++) hh[j] = f2bf(acc[i][j]);
      uint4 pk;
      pk.x = (unsigned)hh[0] | ((unsigned)hh[1] << 16);
      pk.y = (unsigned)hh[2] | ((unsigned)hh[3] << 16);
      pk.z = (unsigned)hh[4] | ((unsigned)hh[5] << 16);
      pk.w = (unsigned)hh[6] | ((unsigned)hh[7] << 16);
      *(uint4*)&xhb[(size_t)row*C1 + tx*8] = pk;
    }
    float s = 0.f, d = 0.f;
    #pragma unroll
    for (int j = 0; j < 8; j++){ s += acc[i][j]*asv[j]; d += acc[i][j]*adv[j]; }
    s += __shfl_xor(s, 1); s += __shfl_xor(s, 2); s += __shfl_xor(s, 4);
    d += __shfl_xor(d, 1); d += __shfl_xor(d, 2); d += __shfl_xor(d, 4);
    if (ok && (tx & 7) == 0){
      as_o[row*2 + h] = s;
      ad_o[row*2 + h] = d;
    }
  }
}

// ---------------- K7: layer-1 aggregation; 16 lanes per node, no barriers ----------------
__global__ void __launch_bounds__(256) k_agg1(const unsigned short* __restrict__ xhb,
    const int* __restrict__ rowptr, const float4* __restrict__ erec,
    const float* __restrict__ as1, const float* __restrict__ ad1,
    const float* __restrict__ b1, float* __restrict__ h1){
  __shared__ float2 eC[NPB1][CAPN+1];   // interleaved (e0,e1) — padded row kills bank conflicts
  __shared__ int    sC[NPB1][CAPN+1];
  int t = threadIdx.x;
  int g = t >> 4, l = t & 15;
  int n = blockIdx.x*NPB1 + g;
  if (n >= N_NODES) return;
  int beg = rowptr[n], end = rowptr[n+1];
  int deg = end - beg;
  float2 adn = *(const float2*)&ad1[n*2];
  bool cached = (deg <= CAPN);

  // phase A: exp(logit) -> LDS (group-local), sums via 4-step shuffle
  float s0 = 0.f, s1 = 0.f, la0 = 0.f, la1 = 0.f;
  for (int i = l; i < deg; i += 16){
    float4 r = erec[(size_t)beg + i];
    int s = __float_as_int(r.x);
    float2 a = *(const float2*)&as1[s*2];
    float e0 = expf(lrelu(a.x + adn.x + r.y));
    float e1 = expf(lrelu(a.y + adn.y + r.z));
    if (cached){ sC[g][i] = s * C1; eC[g][i] = make_float2(e0, e1); }
    s0 += e0; s1 += e1; la0 += r.y; la1 += r.z;
  }
  #pragma unroll
  for (int off = 1; off < 16; off <<= 1){
    s0 += __shfl_xor(s0, off); s1 += __shfl_xor(s1, off);
    la0 += __shfl_xor(la0, off); la1 += __shfl_xor(la1, off);
  }
  float inv = 1.f / fmaxf((float)deg, 1.f);
  float2 asn = *(const float2*)&as1[n*2];
  float sl0 = lrelu(asn.x + adn.x + la0*inv);
  float sl1 = lrelu(asn.y + adn.y + la1*inv);
  float es0 = expf(sl0), es1 = expf(sl1);
  float S0 = s0 + es0 + 1e-16f;
  float S1 = s1 + es1 + 1e-16f;

  // phase B: per edge — e broadcast from LDS, 16 lanes x 16B coalesced row
  int head = l >> 3;                   // lane 0..7 head0 (cols 0..63), 8..15 head1
  float acc[8];
  #pragma unroll
  for (int j = 0; j < 8; j++) acc[j] = 0.f;
  if (cached){
    for (int k = 0; k < deg; k++){
      float2 e2 = eC[g][k];
      float e = head ? e2.y : e2.x;
      uint4 r = *(const uint4*)&xhb[sC[g][k] + l*8];
      acc[0] += e*bfl(r.x); acc[1] += e*bfh(r.x);
      acc[2] += e*bfl(r.y); acc[3] += e*bfh(r.y);
      acc[4] += e*bfl(r.z); acc[5] += e*bfh(r.z);
      acc[6] += e*bfl(r.w); acc[7] += e*bfh(r.w);
    }
  } else {
    // fallback (deg > CAPN): recompute e per edge, group-local, ~never taken
    for (int k = 0; k < deg; k++){
      float4 rr = erec[(size_t)beg + k];
      int s = __float_as_int(rr.x);
      float2 a = *(const float2*)&as1[s*2];
      float e = head ? expf(lrelu(a.y + adn.y + rr.z))
                     : expf(lrelu(a.x + adn.x + rr.y));
      uint4 r = *(const uint4*)&xhb[(size_t)s*C1 + l*8];
      acc[0] += e*bfl(r.x); acc[1] += e*bfh(r.x);
      acc[2] += e*bfl(r.y); acc[3] += e*bfh(r.y);
      acc[4] += e*bfl(r.z); acc[5] += e*bfh(r.z);
      acc[6] += e*bfl(r.w); acc[7] += e*bfh(r.w);
    }
  }
  // epilogue: each lane owns its 8 cols — no cross-lane combine
  float es = head ? es1 : es0;
  float den = head ? S1 : S0;
  uint4 r = *(const uint4*)&xhb[(size_t)n*C1 + l*8];
  float xs8[8];
  xs8[0]=bfl(r.x); xs8[1]=bfh(r.x); xs8[2]=bfl(r.y); xs8[3]=bfh(r.y);
  xs8[4]=bfl(r.z); xs8[5]=bfh(r.z); xs8[6]=bfl(r.w); xs8[7]=bfh(r.w);
  float o[8];
  #pragma unroll
  for (int j = 0; j < 8; j++){
    float v = (acc[j] + es*xs8[j]) / den + b1[l*8 + j];
    o[j] = v > 0.f ? v : expm1f(v);   // ELU
  }
  *(float4*)&h1[(size_t)n*C1 + l*8]     = make_float4(o[0],o[1],o[2],o[3]);
  *(float4*)&h1[(size_t)n*C1 + l*8 + 4] = make_float4(o[4],o[5],o[6],o[7]);
}

// ---------------- K8: xh2 = h1 @ W2 (register-tiled, fused att2, bf16 out) ----------------
#define T2_ROWS 128
#define T2_KK   32
__global__ void __launch_bounds__(256) k_gemm2(const float* __restrict__ h1,
    const float* __restrict__ W2, const float* __restrict__ a_src2,
    const float* __restrict__ a_dst2,
    unsigned short* __restrict__ xh2b, float* __restrict__ as_o, float* __restrict__ ad_o){
  __shared__ float hs[T2_ROWS][T2_KK+1];
  __shared__ float ws[F_IN*OUT_C];     // full W2, 20.5 KB
  int tid = threadIdx.x;
  int tx = tid & 7, ty = tid >> 3;     // tx: 8 col-groups of 5, ty: 32 row-groups of 4
  int r0 = blockIdx.x * T2_ROWS;
  for (int i = tid; i < F_IN*OUT_C/4; i += 256)
    ((float4*)ws)[i] = ((const float4*)W2)[i];
  float acc[4][5];
  #pragma unroll
  for (int i = 0; i < 4; i++)
    #pragma unroll
    for (int j = 0; j < 5; j++) acc[i][j] = 0.f;

  for (int kb = 0; kb < F_IN; kb += T2_KK){
    __syncthreads();
    for (int i = tid; i < T2_ROWS*(T2_KK/4); i += 256){
      int r = i >> 3, c4 = (i & 7) * 4;
      int row = r0 + r;
      float4 v = (row < N_NODES) ? *(const float4*)&h1[(size_t)row*F_IN + kb + c4]
                                 : make_float4(0.f,0.f,0.f,0.f);
      hs[r][c4+0]=v.x; hs[r][c4+1]=v.y; hs[r][c4+2]=v.z; hs[r][c4+3]=v.w;
    }
    __syncthreads();
    #pragma unroll 4
    for (int k = 0; k < T2_KK; k++){
      float a[4], b[5];
      #pragma unroll
      for (int i = 0; i < 4; i++) a[i] = hs[ty*4 + i][k];
      #pragma unroll
      for (int j = 0; j < 5; j++) b[j] = ws[(kb + k)*OUT_C + tx*5 + j];
      #pragma unroll
      for (int i = 0; i < 4; i++)
        #pragma unroll
        for (int j = 0; j < 5; j++)
          acc[i][j] += a[i]*b[j];
    }
  }
  float asv[5], adv[5];
  #pragma unroll
  for (int j = 0; j < 5; j++){
    asv[j] = a_src2[tx*5 + j];
    adv[j] = a_dst2[tx*5 + j];
  }
  #pragma unroll
  for (int i = 0; i < 4; i++){
    int row = r0 + ty*4 + i;
    bool ok = row < N_NODES;
    if (ok){
      #pragma unroll
      for (int j = 0; j < 5; j++)
        xh2b[(size_t)row*OUT_C + tx*5 + j] = f2bf(acc[i][j]);
    }
    float s = 0.f, d = 0.f;
    #pragma unroll
    for (int j = 0; j < 5; j++){ s += acc[i][j]*asv[j]; d += acc[i][j]*adv[j]; }
    s += __shfl_xor(s, 1); s += __shfl_xor(s, 2); s += __shfl_xor(s, 4);
    d += __shfl_xor(d, 1); d += __shfl_xor(d, 2); d += __shfl_xor(d, 4);
    if (ok && tx == 0){
      as_o[row] = s;
      ad_o[row] = d;
    }
  }
}

// ---------------- K10: layer-2 aggregation + log_softmax; 32 lanes per node ----------------
__global__ void __launch_bounds__(256) k_agg2(const unsigned short* __restrict__ xh2b,
    const int* __restrict__ rowptr, const float4* __restrict__ erec,
    const float* __restrict__ as2, const float* __restrict__ ad2,
    const float* __restrict__ b2, float* __restrict__ out){
  __shared__ float eC[NPB2][CAPN+1];
  __shared__ int   sC[NPB2][CAPN+1];
  int t = threadIdx.x;
  int g = t >> 5, l = t & 31;
  int n = blockIdx.x*NPB2 + g;
  if (n >= N_NODES) return;
  int beg = rowptr[n], end = rowptr[n+1];
  int deg = end - beg;
  float adv = ad2[n];
  bool cached = (deg <= CAPN);

  // phase A
  float ss = 0.f, la = 0.f;
  for (int i = l; i < deg; i += 32){
    float4 r = erec[(size_t)beg + i];
    int s = __float_as_int(r.x);
    float e = expf(lrelu(as2[s] + adv + r.w));
    if (cached){ sC[g][i] = s * OUT_C; eC[g][i] = e; }
    ss += e; la += r.w;
  }
  #pragma unroll
  for (int off = 1; off < 32; off <<= 1){
    ss += __shfl_xor(ss, off);
    la += __shfl_xor(la, off);
  }
  float inv = 1.f / fmaxf((float)deg, 1.f);
  float sl = lrelu(as2[n] + adv + la*inv);
  float es = expf(sl);
  float S = ss + es + 1e-16f;

  // phase B: lanes 0..19 own cols {2l, 2l+1}
  float a0 = 0.f, a1 = 0.f;
  if (l < 20){
    if (cached){
      for (int k = 0; k < deg; k++){
        float e = eC[g][k];
        unsigned u = *(const unsigned*)&xh2b[sC[g][k] + l*2];
        a0 += e*bfl(u); a1 += e*bfh(u);
      }
    } else {
      for (int k = 0; k < deg; k++){
        float4 rr = erec[(size_t)beg + k];
        int s = __float_as_int(rr.x);
        float e = expf(lrelu(as2[s] + adv + rr.w));
        unsigned u = *(const unsigned*)&xh2b[(size_t)s*OUT_C + l*2];
        a0 += e*bfl(u); a1 += e*bfh(u);
      }
    }
  }
  float o0 = -INFINITY, o1 = -INFINITY;
  if (l < 20){
    unsigned u = *(const unsigned*)&xh2b[(size_t)n*OUT_C + l*2];
    o0 = (a0 + es*bfl(u)) / S + b2[l*2 + 0];
    o1 = (a1 + es*bfh(u)) / S + b2[l*2 + 1];
  }
  // log_softmax over 40 cols (2 per lane in lanes 0..19)
  float mm = fmaxf(o0, o1);
  #pragma unroll
  for (int off = 1; off < 32; off <<= 1) mm = fmaxf(mm, __shfl_xor(mm, off));
  float e = (l < 20) ? (expf(o0 - mm) + expf(o1 - mm)) : 0.f;
  #pragma unroll
  for (int off = 1; off < 32; off <<= 1) e += __shfl_xor(e, off);
  if (l < 20){
    float lse = logf(e);
    out[(size_t)n*OUT_C + l*2 + 0] = o0 - mm - lse;
    out[(size_t)n*OUT_C + l*2 + 1] = o1 - mm - lse;
  }
}

// ---------------- host launcher ----------------
extern "C" void kernel_launch(void* const* d_in, const int* in_sizes, int n_in,
                              void* d_out, int out_size, void* d_ws, size_t ws_size,
                              hipStream_t stream){
  const float* x        = (const float*)d_in[0];
  const int*   ei       = (const int*)  d_in[1];
  const float* eattr    = (const float*)d_in[2];
  const float* W1       = (const float*)d_in[3];
  const float* att_src1 = (const float*)d_in[4];
  const float* att_dst1 = (const float*)d_in[5];
  const float* We1      = (const float*)d_in[6];
  const float* att_e1   = (const float*)d_in[7];
  const float* b1       = (const float*)d_in[8];
  const float* W2       = (const float*)d_in[9];
  const float* att_src2 = (const float*)d_in[10];
  const float* att_dst2 = (const float*)d_in[11];
  const float* We2      = (const float*)d_in[12];
  const float* att_e2   = (const float*)d_in[13];
  const float* b2       = (const float*)d_in[14];
  const int* src = ei;
  const int* dst = ei + N_EDGES;

  float* wsf    = (float*)d_ws;
  int*   cnt     = (int*)(wsf + O_CNT);
  int*   fill    = (int*)(wsf + O_FILL);
  int*   rowptr  = (int*)(wsf + O_ROWPTR);
  int*   stmp    = (int*)(wsf + O_STMP);
  int*   bsum    = (int*)(wsf + O_BSUM);
  int*   boff    = (int*)(wsf + O_BOFF);
  float4* erec   = (float4*)(wsf + O_EREC);
  float* weatt   = wsf + O_WEATT;
  unsigned short* xhb  = (unsigned short*)(wsf + O_XHB);
  float* as1     = wsf + O_AS1;
  float* ad1     = wsf + O_AD1;
  float* h1      = wsf + O_H1;
  unsigned short* xh2b = (unsigned short*)(wsf + O_XH2B);
  float* as2     = wsf + O_AS2;
  float* ad2     = wsf + O_AD2;
  float* out     = (float*)d_out;

  hipMemsetAsync(wsf + O_CNT, 0, O_ZERO_END*sizeof(float), stream);

  const int EB = (N_EDGES + 255) / 256;

  k_weatt  <<<1, 64, 0, stream>>>(We1, att_e1, We2, att_e2, weatt);
  k_count  <<<EB, 256, 0, stream>>>(dst, cnt);
  k_scan1  <<<SCAN_NB, SCAN_B, 0, stream>>>(cnt, stmp, bsum);
  k_scan2  <<<1, SCAN_B, 0, stream>>>(bsum, boff);
  k_scan3  <<<SCAN_NB, SCAN_B, 0, stream>>>(stmp, boff, rowptr);
  k_scatter<<<EB, 256, 0, stream>>>(src, dst, eattr, rowptr, fill, weatt, erec);

  k_gemm1  <<<(N_NODES + T1_ROWS - 1)/T1_ROWS, 256, 0, stream>>>(x, W1, att_src1, att_dst1,
                                                                 xhb, as1, ad1);
  k_agg1   <<<(N_NODES + NPB1 - 1)/NPB1, 256, 0, stream>>>(xhb, rowptr, erec, as1, ad1, b1, h1);

  k_gemm2  <<<(N_NODES + T2_ROWS - 1)/T2_ROWS, 256, 0, stream>>>(h1, W2, att_src2, att_dst2,
                                                                 xh2b, as2, ad2);
  k_agg2   <<<(N_NODES + NPB2 - 1)/NPB2, 256, 0, stream>>>(xh2b, rowptr, erec, as2, ad2, b2, out);
}

// Round 9
// 190.561 us; speedup vs baseline: 1.4264x; 1.1651x over previous
//
#include <hip/hip_runtime.h>
#include <hip/hip_fp16.h>
#include <math.h>

#define N_NODES 50000
#define N_EDGES 800000
#define F_IN    128
#define HID     64
#define HEADS   2
#define C1      128   // HEADS*HID
#define OUT_C   40
#define EDIM    5
#define NEG_SLOPE 0.2f
#define CAPN    64    // per-node LDS edge cache (Poisson(16): P(deg>64)~1e-20; fallback kept)
#define NPB1    16    // nodes per block, layer-1 agg (16 lanes/node)
#define NPB2    8     // nodes per block, layer-2 agg (32 lanes/node)
#define SCAN_B  256
#define SCAN_NB ((N_NODES + SCAN_B - 1) / SCAN_B)   // 196

// ---------------- workspace layout (element offsets, 4B units) ----------------
constexpr size_t pad64(size_t n){ return (n + 63) / 64 * 64; }
constexpr size_t O_CNT      = 0;
constexpr size_t O_ZERO_END = O_CNT      + pad64(N_NODES);
constexpr size_t O_RANK     = O_ZERO_END;
constexpr size_t O_ROWPTR   = O_RANK     + pad64(N_EDGES);
constexpr size_t O_STMP     = O_ROWPTR   + pad64(N_NODES+1);
constexpr size_t O_BSUM     = O_STMP     + pad64(N_NODES);
constexpr size_t O_BOFF     = O_BSUM     + pad64(SCAN_NB);
constexpr size_t O_EREC     = O_BOFF     + pad64(SCAN_NB);    // uint2 per edge {src|l2h, l0h|l1h}
constexpr size_t O_WEATT    = O_EREC     + pad64((size_t)N_EDGES*2);
constexpr size_t O_XHB      = O_WEATT    + 64;                       // bf16 [N][128]
constexpr size_t O_AS1      = O_XHB      + pad64((size_t)N_NODES*C1/2);
constexpr size_t O_AD1      = O_AS1      + pad64((size_t)N_NODES*2);
constexpr size_t O_H1       = O_AD1      + pad64((size_t)N_NODES*2);
constexpr size_t O_XH2B     = O_H1       + pad64((size_t)N_NODES*C1);  // bf16 [N][40]
constexpr size_t O_AS2      = O_XH2B     + pad64((size_t)N_NODES*OUT_C/2);
constexpr size_t O_AD2      = O_AS2      + pad64(N_NODES);

__device__ __forceinline__ float lrelu(float v){ return v >= 0.f ? v : NEG_SLOPE*v; }
__device__ __forceinline__ float bfl(unsigned u){ return __uint_as_float(u << 16); }
__device__ __forceinline__ float bfh(unsigned u){ return __uint_as_float(u & 0xFFFF0000u); }
__device__ __forceinline__ unsigned short f2bf(float f){
  unsigned u = __float_as_uint(f);
  return (unsigned short)((u + 0x7FFFu + ((u >> 16) & 1u)) >> 16);   // RNE
}
__device__ __forceinline__ unsigned f2h(float f){
  return (unsigned)__half_as_ushort(__float2half(f));
}
__device__ __forceinline__ float h2f(unsigned u){
  return __half2float(__ushort_as_half((unsigned short)(u & 0xFFFFu)));
}

// ---------------- K0: tiny attention-projection matrices ----------------
__global__ void k_weatt(const float* __restrict__ We1, const float* __restrict__ ae1,
                        const float* __restrict__ We2, const float* __restrict__ ae2,
                        float* __restrict__ weatt){
  int t = threadIdx.x;
  if (t < 10){
    int k = t >> 1, h = t & 1;
    float s = 0.f;
    for (int c = 0; c < HID; c++) s += We1[k*C1 + h*HID + c] * ae1[h*HID + c];
    weatt[k*2 + h] = s;
  } else if (t < 15){
    int k = t - 10;
    float s = 0.f;
    for (int c = 0; c < OUT_C; c++) s += We2[k*OUT_C + c] * ae2[c];
    weatt[10 + k] = s;
  }
}

// ---------------- K1: in-degree + per-edge rank (atomic return value is free) ----------------
__global__ void k_count(const int* __restrict__ dst, int* __restrict__ cnt,
                        int* __restrict__ rank){
  int e = blockIdx.x*blockDim.x + threadIdx.x;
  if (e >= N_EDGES) return;
  rank[e] = atomicAdd(&cnt[dst[e]], 1);
}

// ---------------- K2: device-wide exclusive scan, 3 wide dispatches ----------------
__global__ void __launch_bounds__(SCAN_B) k_scan1(const int* __restrict__ cnt,
                                                  int* __restrict__ stmp,
                                                  int* __restrict__ bsum){
  int blk = blockIdx.x, t = threadIdx.x;
  int i = blk*SCAN_B + t;
  int v = (i < N_NODES) ? cnt[i] : 0;
  int lane = t & 63, w = t >> 6;
  int x = v;
  #pragma unroll
  for (int off = 1; off < 64; off <<= 1){
    int y = __shfl_up(x, off);
    if (lane >= off) x += y;
  }
  __shared__ int wsum[SCAN_B/64];
  if (lane == 63) wsum[w] = x;
  __syncthreads();
  int add = 0;
  for (int k = 0; k < w; k++) add += wsum[k];
  x += add;
  if (i < N_NODES) stmp[i] = x;
  if (t == SCAN_B-1) bsum[blk] = x;
}

__global__ void __launch_bounds__(SCAN_B) k_scan2(const int* __restrict__ bsum,
                                                  int* __restrict__ boff){
  int t = threadIdx.x;
  int v = (t < SCAN_NB) ? bsum[t] : 0;
  int lane = t & 63, w = t >> 6;
  int x = v;
  #pragma unroll
  for (int off = 1; off < 64; off <<= 1){
    int y = __shfl_up(x, off);
    if (lane >= off) x += y;
  }
  __shared__ int wsum[SCAN_B/64];
  if (lane == 63) wsum[w] = x;
  __syncthreads();
  int add = 0;
  for (int k = 0; k < w; k++) add += wsum[k];
  x += add;                      // inclusive
  if (t < SCAN_NB) boff[t] = x - v;  // exclusive
}

__global__ void __launch_bounds__(SCAN_B) k_scan3(const int* __restrict__ stmp,
                                                  const int* __restrict__ boff,
                                                  int* __restrict__ rowptr){
  int blk = blockIdx.x, t = threadIdx.x;
  int i = blk*SCAN_B + t;
  if (i < N_NODES) rowptr[i+1] = stmp[i] + boff[blk];
  if (i == 0) rowptr[0] = 0;
}

// ---------------- K3: scatter edges into CSR, atomic-free, 8B packed records ----------------
__global__ void k_scatter(const int* __restrict__ src, const int* __restrict__ dst,
                          const int* __restrict__ rank,
                          const float* __restrict__ eattr, const int* __restrict__ rowptr,
                          const float* __restrict__ weatt,
                          uint2* __restrict__ erec){
  int e = blockIdx.x*blockDim.x + threadIdx.x;
  if (e >= N_EDGES) return;
  int d = dst[e];
  int pos = rowptr[d] + rank[e];
  float a[EDIM];
  #pragma unroll
  for (int k = 0; k < EDIM; k++) a[k] = eattr[e*EDIM + k];
  float l0 = 0.f, l1 = 0.f, l2 = 0.f;
  #pragma unroll
  for (int k = 0; k < EDIM; k++){
    l0 += a[k]*weatt[k*2 + 0];
    l1 += a[k]*weatt[k*2 + 1];
    l2 += a[k]*weatt[10 + k];
  }
  unsigned w0 = (unsigned)src[e] | (f2h(l2) << 16);
  unsigned w1 = f2h(l0) | (f2h(l1) << 16);
  erec[pos] = make_uint2(w0, w1);
}

// ---------------- K5: xh1 = x @ W1 (register-tiled 128x128, fused att1, bf16 out) ----------------
#define T1_ROWS 128
#define T1_KK   32
__global__ void __launch_bounds__(256) k_gemm1(const float* __restrict__ x,
                                               const float* __restrict__ W,
                                               const float* __restrict__ a_src,
                                               const float* __restrict__ a_dst,
                                               unsigned short* __restrict__ xhb,
                                               float* __restrict__ as_o,
                                               float* __restrict__ ad_o){
  __shared__ float xs[T1_ROWS][T1_KK+1];
  __shared__ float ws[T1_KK][C1];
  int tid = threadIdx.x;
  int tx = tid & 15, ty = tid >> 4;
  int r0 = blockIdx.x * T1_ROWS;
  float acc[8][8];
  #pragma unroll
  for (int i = 0; i < 8; i++)
    #pragma unroll
    for (int j = 0; j < 8; j++) acc[i][j] = 0.f;

  for (int kb = 0; kb < F_IN; kb += T1_KK){
    __syncthreads();
    for (int i = tid; i < T1_ROWS*(T1_KK/4); i += 256){
      int r = i >> 3, c4 = (i & 7) * 4;
      int row = r0 + r;
      float4 v = (row < N_NODES) ? *(const float4*)&x[(size_t)row*F_IN + kb + c4]
                                 : make_float4(0.f,0.f,0.f,0.f);
      xs[r][c4+0]=v.x; xs[r][c4+1]=v.y; xs[r][c4+2]=v.z; xs[r][c4+3]=v.w;
    }
    for (int i = tid; i < T1_KK*(C1/4); i += 256){
      int k = i >> 5, c4 = (i & 31) * 4;
      *(float4*)&ws[k][c4] = *(const float4*)&W[(size_t)(kb + k)*C1 + c4];
    }
    __syncthreads();
    #pragma unroll 4
    for (int k = 0; k < T1_KK; k++){
      float a[8], b[8];
      #pragma unroll
      for (int i = 0; i < 8; i++) a[i] = xs[ty*8 + i][k];
      float4 b0 = *(const float4*)&ws[k][tx*8];
      float4 b1 = *(const float4*)&ws[k][tx*8+4];
      b[0]=b0.x; b[1]=b0.y; b[2]=b0.z; b[3]=b0.w;
      b[4]=b1.x; b[5]=b1.y; b[6]=b1.z; b[7]=b1.w;
      #pragma unroll
      for (int i = 0; i < 8; i++)
        #pragma unroll
        for (int j = 0; j < 8; j++)
          acc[i][j] += a[i]*b[j];
    }
  }
  float asv[8], adv[8];
  #pragma unroll
  for (int j = 0; j < 8; j++){
    asv[j] = a_src[tx*8 + j];
    adv[j] = a_dst[tx*8 + j];
  }
  int h = tx >> 3;
  #pragma unroll
  for (int i = 0; i < 8; i++){
    int row = r0 + ty*8 + i;
    bool ok = row < N_NODES;
    if (ok){
      unsigned short hh[8];
      #pragma unroll
      for (int j = 0; j < 8; j++) hh[j] = f2bf(acc[i][j]);
      uint4 pk;
      pk.x = (unsigned)hh[0] | ((unsigned)hh[1] << 16);
      pk.y = (unsigned)hh[2] | ((unsigned)hh[3] << 16);
      pk.z = (unsigned)hh[4] | ((unsigned)hh[5] << 16);
      pk.w = (unsigned)hh[6] | ((unsigned)hh[7] << 16);
      *(uint4*)&xhb[(size_t)row*C1 + tx*8] = pk;
    }
    float s = 0.f, d = 0.f;
    #pragma unroll
    for (int j = 0; j < 8; j++){ s += acc[i][j]*asv[j]; d += acc[i][j]*adv[j]; }
    s += __shfl_xor(s, 1); s += __shfl_xor(s, 2); s += __shfl_xor(s, 4);
    d += __shfl_xor(d, 1); d += __shfl_xor(d, 2); d += __shfl_xor(d, 4);
    if (ok && (tx & 7) == 0){
      as_o[row*2 + h] = s;
      ad_o[row*2 + h] = d;
    }
  }
}

// ---------------- K7: layer-1 aggregation; 16 lanes per node, no barriers ----------------
__global__ void __launch_bounds__(256) k_agg1(const unsigned short* __restrict__ xhb,
    const int* __restrict__ rowptr, const uint2* __restrict__ erec,
    const float* __restrict__ as1, const float* __restrict__ ad1,
    const float* __restrict__ b1, float* __restrict__ h1){
  __shared__ float2 eC[NPB1][CAPN+1];   // interleaved (e0,e1) — padded row kills bank conflicts
  __shared__ int    sC[NPB1][CAPN+1];
  int t = threadIdx.x;
  int g = t >> 4, l = t & 15;
  int n = blockIdx.x*NPB1 + g;
  if (n >= N_NODES) return;
  int beg = rowptr[n], end = rowptr[n+1];
  int deg = end - beg;
  float2 adn = *(const float2*)&ad1[n*2];
  bool cached = (deg <= CAPN);

  // phase A: exp(logit) -> LDS (group-local), sums via 4-step shuffle
  float s0 = 0.f, s1 = 0.f, la0 = 0.f, la1 = 0.f;
  for (int i = l; i < deg; i += 16){
    uint2 r = erec[(size_t)beg + i];
    int s = r.x & 0xFFFFu;
    float al0 = h2f(r.y), al1 = h2f(r.y >> 16);
    float2 a = *(const float2*)&as1[s*2];
    float e0 = expf(lrelu(a.x + adn.x + al0));
    float e1 = expf(lrelu(a.y + adn.y + al1));
    if (cached){ sC[g][i] = s * C1; eC[g][i] = make_float2(e0, e1); }
    s0 += e0; s1 += e1; la0 += al0; la1 += al1;
  }
  #pragma unroll
  for (int off = 1; off < 16; off <<= 1){
    s0 += __shfl_xor(s0, off); s1 += __shfl_xor(s1, off);
    la0 += __shfl_xor(la0, off); la1 += __shfl_xor(la1, off);
  }
  float inv = 1.f / fmaxf((float)deg, 1.f);
  float2 asn = *(const float2*)&as1[n*2];
  float sl0 = lrelu(asn.x + adn.x + la0*inv);
  float sl1 = lrelu(asn.y + adn.y + la1*inv);
  float es0 = expf(sl0), es1 = expf(sl1);
  float S0 = s0 + es0 + 1e-16f;
  float S1 = s1 + es1 + 1e-16f;

  // phase B: per edge — e broadcast from LDS, 16 lanes x 16B coalesced row
  int head = l >> 3;                   // lane 0..7 head0 (cols 0..63), 8..15 head1
  float acc[8];
  #pragma unroll
  for (int j = 0; j < 8; j++) acc[j] = 0.f;
  if (cached){
    for (int k = 0; k < deg; k++){
      float2 e2 = eC[g][k];
      float e = head ? e2.y : e2.x;
      uint4 r = *(const uint4*)&xhb[sC[g][k] + l*8];
      acc[0] += e*bfl(r.x); acc[1] += e*bfh(r.x);
      acc[2] += e*bfl(r.y); acc[3] += e*bfh(r.y);
      acc[4] += e*bfl(r.z); acc[5] += e*bfh(r.z);
      acc[6] += e*bfl(r.w); acc[7] += e*bfh(r.w);
    }
  } else {
    // fallback (deg > CAPN): recompute e per edge, group-local, ~never taken
    for (int k = 0; k < deg; k++){
      uint2 rr = erec[(size_t)beg + k];
      int s = rr.x & 0xFFFFu;
      float2 a = *(const float2*)&as1[s*2];
      float e = head ? expf(lrelu(a.y + adn.y + h2f(rr.y >> 16)))
                     : expf(lrelu(a.x + adn.x + h2f(rr.y)));
      uint4 r = *(const uint4*)&xhb[(size_t)s*C1 + l*8];
      acc[0] += e*bfl(r.x); acc[1] += e*bfh(r.x);
      acc[2] += e*bfl(r.y); acc[3] += e*bfh(r.y);
      acc[4] += e*bfl(r.z); acc[5] += e*bfh(r.z);
      acc[6] += e*bfl(r.w); acc[7] += e*bfh(r.w);
    }
  }
  // epilogue: each lane owns its 8 cols — no cross-lane combine
  float es = head ? es1 : es0;
  float den = head ? S1 : S0;
  uint4 r = *(const uint4*)&xhb[(size_t)n*C1 + l*8];
  float xs8[8];
  xs8[0]=bfl(r.x); xs8[1]=bfh(r.x); xs8[2]=bfl(r.y); xs8[3]=bfh(r.y);
  xs8[4]=bfl(r.z); xs8[5]=bfh(r.z); xs8[6]=bfl(r.w); xs8[7]=bfh(r.w);
  float o[8];
  #pragma unroll
  for (int j = 0; j < 8; j++){
    float v = (acc[j] + es*xs8[j]) / den + b1[l*8 + j];
    o[j] = v > 0.f ? v : expm1f(v);   // ELU
  }
  *(float4*)&h1[(size_t)n*C1 + l*8]     = make_float4(o[0],o[1],o[2],o[3]);
  *(float4*)&h1[(size_t)n*C1 + l*8 + 4] = make_float4(o[4],o[5],o[6],o[7]);
}

// ---------------- K8: xh2 = h1 @ W2 (register-tiled, fused att2, bf16 out) ----------------
#define T2_ROWS 128
#define T2_KK   32
__global__ void __launch_bounds__(256) k_gemm2(const float* __restrict__ h1,
    const float* __restrict__ W2, const float* __restrict__ a_src2,
    const float* __restrict__ a_dst2,
    unsigned short* __restrict__ xh2b, float* __restrict__ as_o, float* __restrict__ ad_o){
  __shared__ float hs[T2_ROWS][T2_KK+1];
  __shared__ float ws[F_IN*OUT_C];     // full W2, 20.5 KB
  int tid = threadIdx.x;
  int tx = tid & 7, ty = tid >> 3;     // tx: 8 col-groups of 5, ty: 32 row-groups of 4
  int r0 = blockIdx.x * T2_ROWS;
  for (int i = tid; i < F_IN*OUT_C/4; i += 256)
    ((float4*)ws)[i] = ((const float4*)W2)[i];
  float acc[4][5];
  #pragma unroll
  for (int i = 0; i < 4; i++)
    #pragma unroll
    for (int j = 0; j < 5; j++) acc[i][j] = 0.f;

  for (int kb = 0; kb < F_IN; kb += T2_KK){
    __syncthreads();
    for (int i = tid; i < T2_ROWS*(T2_KK/4); i += 256){
      int r = i >> 3, c4 = (i & 7) * 4;
      int row = r0 + r;
      float4 v = (row < N_NODES) ? *(const float4*)&h1[(size_t)row*F_IN + kb + c4]
                                 : make_float4(0.f,0.f,0.f,0.f);
      hs[r][c4+0]=v.x; hs[r][c4+1]=v.y; hs[r][c4+2]=v.z; hs[r][c4+3]=v.w;
    }
    __syncthreads();
    #pragma unroll 4
    for (int k = 0; k < T2_KK; k++){
      float a[4], b[5];
      #pragma unroll
      for (int i = 0; i < 4; i++) a[i] = hs[ty*4 + i][k];
      #pragma unroll
      for (int j = 0; j < 5; j++) b[j] = ws[(kb + k)*OUT_C + tx*5 + j];
      #pragma unroll
      for (int i = 0; i < 4; i++)
        #pragma unroll
        for (int j = 0; j < 5; j++)
          acc[i][j] += a[i]*b[j];
    }
  }
  float asv[5], adv[5];
  #pragma unroll
  for (int j = 0; j < 5; j++){
    asv[j] = a_src2[tx*5 + j];
    adv[j] = a_dst2[tx*5 + j];
  }
  #pragma unroll
  for (int i = 0; i < 4; i++){
    int row = r0 + ty*4 + i;
    bool ok = row < N_NODES;
    if (ok){
      #pragma unroll
      for (int j = 0; j < 5; j++)
        xh2b[(size_t)row*OUT_C + tx*5 + j] = f2bf(acc[i][j]);
    }
    float s = 0.f, d = 0.f;
    #pragma unroll
    for (int j = 0; j < 5; j++){ s += acc[i][j]*asv[j]; d += acc[i][j]*adv[j]; }
    s += __shfl_xor(s, 1); s += __shfl_xor(s, 2); s += __shfl_xor(s, 4);
    d += __shfl_xor(d, 1); d += __shfl_xor(d, 2); d += __shfl_xor(d, 4);
    if (ok && tx == 0){
      as_o[row] = s;
      ad_o[row] = d;
    }
  }
}

// ---------------- K10: layer-2 aggregation + log_softmax; 32 lanes per node ----------------
__global__ void __launch_bounds__(256) k_agg2(const unsigned short* __restrict__ xh2b,
    const int* __restrict__ rowptr, const uint2* __restrict__ erec,
    const float* __restrict__ as2, const float* __restrict__ ad2,
    const float* __restrict__ b2, float* __restrict__ out){
  __shared__ float eC[NPB2][CAPN+1];
  __shared__ int   sC[NPB2][CAPN+1];
  int t = threadIdx.x;
  int g = t >> 5, l = t & 31;
  int n = blockIdx.x*NPB2 + g;
  if (n >= N_NODES) return;
  int beg = rowptr[n], end = rowptr[n+1];
  int deg = end - beg;
  float adv = ad2[n];
  bool cached = (deg <= CAPN);

  // phase A
  float ss = 0.f, la = 0.f;
  for (int i = l; i < deg; i += 32){
    uint2 r = erec[(size_t)beg + i];
    int s = r.x & 0xFFFFu;
    float al2 = h2f(r.x >> 16);
    float e = expf(lrelu(as2[s] + adv + al2));
    if (cached){ sC[g][i] = s * OUT_C; eC[g][i] = e; }
    ss += e; la += al2;
  }
  #pragma unroll
  for (int off = 1; off < 32; off <<= 1){
    ss += __shfl_xor(ss, off);
    la += __shfl_xor(la, off);
  }
  float inv = 1.f / fmaxf((float)deg, 1.f);
  float sl = lrelu(as2[n] + adv + la*inv);
  float es = expf(sl);
  float S = ss + es + 1e-16f;

  // phase B: lanes 0..19 own cols {2l, 2l+1}
  float a0 = 0.f, a1 = 0.f;
  if (l < 20){
    if (cached){
      for (int k = 0; k < deg; k++){
        float e = eC[g][k];
        unsigned u = *(const unsigned*)&xh2b[sC[g][k] + l*2];
        a0 += e*bfl(u); a1 += e*bfh(u);
      }
    } else {
      for (int k = 0; k < deg; k++){
        uint2 rr = erec[(size_t)beg + k];
        int s = rr.x & 0xFFFFu;
        float e = expf(lrelu(as2[s] + adv + h2f(rr.x >> 16)));
        unsigned u = *(const unsigned*)&xh2b[(size_t)s*OUT_C + l*2];
        a0 += e*bfl(u); a1 += e*bfh(u);
      }
    }
  }
  float o0 = -INFINITY, o1 = -INFINITY;
  if (l < 20){
    unsigned u = *(const unsigned*)&xh2b[(size_t)n*OUT_C + l*2];
    o0 = (a0 + es*bfl(u)) / S + b2[l*2 + 0];
    o1 = (a1 + es*bfh(u)) / S + b2[l*2 + 1];
  }
  // log_softmax over 40 cols (2 per lane in lanes 0..19)
  float mm = fmaxf(o0, o1);
  #pragma unroll
  for (int off = 1; off < 32; off <<= 1) mm = fmaxf(mm, __shfl_xor(mm, off));
  float e = (l < 20) ? (expf(o0 - mm) + expf(o1 - mm)) : 0.f;
  #pragma unroll
  for (int off = 1; off < 32; off <<= 1) e += __shfl_xor(e, off);
  if (l < 20){
    float lse = logf(e);
    out[(size_t)n*OUT_C + l*2 + 0] = o0 - mm - lse;
    out[(size_t)n*OUT_C + l*2 + 1] = o1 - mm - lse;
  }
}

// ---------------- host launcher ----------------
extern "C" void kernel_launch(void* const* d_in, const int* in_sizes, int n_in,
                              void* d_out, int out_size, void* d_ws, size_t ws_size,
                              hipStream_t stream){
  const float* x        = (const float*)d_in[0];
  const int*   ei       = (const int*)  d_in[1];
  const float* eattr    = (const float*)d_in[2];
  const float* W1       = (const float*)d_in[3];
  const float* att_src1 = (const float*)d_in[4];
  const float* att_dst1 = (const float*)d_in[5];
  const float* We1      = (const float*)d_in[6];
  const float* att_e1   = (const float*)d_in[7];
  const float* b1       = (const float*)d_in[8];
  const float* W2       = (const float*)d_in[9];
  const float* att_src2 = (const float*)d_in[10];
  const float* att_dst2 = (const float*)d_in[11];
  const float* We2      = (const float*)d_in[12];
  const float* att_e2   = (const float*)d_in[13];
  const float* b2       = (const float*)d_in[14];
  const int* src = ei;
  const int* dst = ei + N_EDGES;

  float* wsf    = (float*)d_ws;
  int*   cnt     = (int*)(wsf + O_CNT);
  int*   rank    = (int*)(wsf + O_RANK);
  int*   rowptr  = (int*)(wsf + O_ROWPTR);
  int*   stmp    = (int*)(wsf + O_STMP);
  int*   bsum    = (int*)(wsf + O_BSUM);
  int*   boff    = (int*)(wsf + O_BOFF);
  uint2* erec    = (uint2*)(wsf + O_EREC);
  float* weatt   = wsf + O_WEATT;
  unsigned short* xhb  = (unsigned short*)(wsf + O_XHB);
  float* as1     = wsf + O_AS1;
  float* ad1     = wsf + O_AD1;
  float* h1      = wsf + O_H1;
  unsigned short* xh2b = (unsigned short*)(wsf + O_XH2B);
  float* as2     = wsf + O_AS2;
  float* ad2     = wsf + O_AD2;
  float* out     = (float*)d_out;

  hipMemsetAsync(wsf + O_CNT, 0, O_ZERO_END*sizeof(float), stream);

  const int EB = (N_EDGES + 255) / 256;

  k_weatt  <<<1, 64, 0, stream>>>(We1, att_e1, We2, att_e2, weatt);
  k_count  <<<EB, 256, 0, stream>>>(dst, cnt, rank);
  k_scan1  <<<SCAN_NB, SCAN_B, 0, stream>>>(cnt, stmp, bsum);
  k_scan2  <<<1, SCAN_B, 0, stream>>>(bsum, boff);
  k_scan3  <<<SCAN_NB, SCAN_B, 0, stream>>>(stmp, boff, rowptr);
  k_scatter<<<EB, 256, 0, stream>>>(src, dst, rank, eattr, rowptr, weatt, erec);

  k_gemm1  <<<(N_NODES + T1_ROWS - 1)/T1_ROWS, 256, 0, stream>>>(x, W1, att_src1, att_dst1,
                                                                 xhb, as1, ad1);
  k_agg1   <<<(N_NODES + NPB1 - 1)/NPB1, 256, 0, stream>>>(xhb, rowptr, erec, as1, ad1, b1, h1);

  k_gemm2  <<<(N_NODES + T2_ROWS - 1)/T2_ROWS, 256, 0, stream>>>(h1, W2, att_src2, att_dst2,
                                                                 xh2b, as2, ad2);
  k_agg2   <<<(N_NODES + NPB2 - 1)/NPB2, 256, 0, stream>>>(xh2b, rowptr, erec, as2, ad2, b2, out);
}